// Round 1
// baseline (242.332 us; speedup 1.0000x reference)
//
#include <hip/hip_runtime.h>

typedef unsigned short ushort_t;
typedef unsigned int uint_t;

#define B_ 8192
#define C_ 1000
#define CP_ 1024   /* padded classes */
#define D_ 2048

typedef short bf16x8 __attribute__((ext_vector_type(8)));
typedef float f32x4 __attribute__((ext_vector_type(4)));

typedef const __attribute__((address_space(1))) void* as1_cvp;
typedef __attribute__((address_space(3))) void* as3_vp;
#define GLOAD16(gp, lp) __builtin_amdgcn_global_load_lds((as1_cvp)(gp), (as3_vp)(lp), 16, 0, 0)

__device__ __forceinline__ ushort_t f2bf(float f) {
    uint_t x = __float_as_uint(f);
    uint_t r = (x + 0x7fffu + ((x >> 16) & 1u)) >> 16;
    return (ushort_t)r;
}

__device__ __forceinline__ float waveReduce(float v) {
#pragma unroll
    for (int o = 32; o; o >>= 1) v += __shfl_xor(v, o, 64);
    return v;
}

// ---- prep_z: z (f32) -> z_bf (bf16), zsq[b] = ||z_b||^2. One block per row.
__global__ __launch_bounds__(256) void prep_z(const float* __restrict__ z,
                                              ushort_t* __restrict__ zb,
                                              float* __restrict__ zsq) {
    const int r = blockIdx.x;
    const int t = threadIdx.x;
    const float4* zr = (const float4*)(z + (size_t)r * D_);
    float4 a = zr[t * 2];
    float4 b = zr[t * 2 + 1];
    float vals[8] = {a.x, a.y, a.z, a.w, b.x, b.y, b.z, b.w};
    ushort_t u[8];
    float ss = 0.f;
#pragma unroll
    for (int i = 0; i < 8; i++) { ss += vals[i] * vals[i]; u[i] = f2bf(vals[i]); }
    *(uint4*)(zb + (size_t)r * D_ + t * 8) = *(const uint4*)u;
    ss = waveReduce(ss);
    __shared__ float sb[4];
    if ((t & 63) == 0) sb[t >> 6] = ss;
    __syncthreads();
    if (t == 0) zsq[r] = sb[0] + sb[1] + sb[2] + sb[3];
}

// ---- prep_mu: mu (f32) -> mu_bf (bf16, padded to 1024 rows), musq[c]; pads: 0 / 1e30
__global__ __launch_bounds__(256) void prep_mu(const float* __restrict__ mu,
                                               ushort_t* __restrict__ mub,
                                               float* __restrict__ musq) {
    const int c = blockIdx.x;  // 0..1023
    const int t = threadIdx.x;
    if (c < C_) {
        const float4* mr = (const float4*)(mu + (size_t)c * D_);
        float4 a = mr[t * 2];
        float4 b = mr[t * 2 + 1];
        float vals[8] = {a.x, a.y, a.z, a.w, b.x, b.y, b.z, b.w};
        ushort_t u[8];
        float ss = 0.f;
#pragma unroll
        for (int i = 0; i < 8; i++) { ss += vals[i] * vals[i]; u[i] = f2bf(vals[i]); }
        *(uint4*)(mub + (size_t)c * D_ + t * 8) = *(const uint4*)u;
        ss = waveReduce(ss);
        __shared__ float sb[4];
        if ((t & 63) == 0) sb[t >> 6] = ss;
        __syncthreads();
        if (t == 0) musq[c] = sb[0] + sb[1] + sb[2] + sb[3];
    } else {
        uint4 zero4 = {0, 0, 0, 0};
        *(uint4*)(mub + (size_t)c * D_ + t * 8) = zero4;
        if (t == 0) musq[c] = 1e30f;  // exp(S - 0.5e30) == 0 -> pads vanish from LSE
    }
}

// ---- label_dot: find label from one-hot y, compute zz[b,label] EXACTLY in f32.
__global__ __launch_bounds__(256) void label_dot(const float* __restrict__ y,
                                                 const float* __restrict__ z,
                                                 const float* __restrict__ mu,
                                                 const float* __restrict__ zsq,
                                                 const float* __restrict__ musq,
                                                 float* __restrict__ zzlab) {
    const int r = blockIdx.x;
    const int t = threadIdx.x;
    __shared__ int slab;
    const float* yr = y + (size_t)r * C_;
    for (int i = t; i < C_; i += 256)
        if (yr[i] > 0.5f) slab = i;
    __syncthreads();
    const int lab = slab;
    const float4* zr = (const float4*)(z + (size_t)r * D_);
    const float4* mr = (const float4*)(mu + (size_t)lab * D_);
    float dot = 0.f;
#pragma unroll
    for (int i = t; i < D_ / 4; i += 256) {
        float4 a = zr[i], b = mr[i];
        dot += a.x * b.x + a.y * b.y + a.z * b.z + a.w * b.w;
    }
    dot = waveReduce(dot);
    __shared__ float sb[4];
    if ((t & 63) == 0) sb[t >> 6] = dot;
    __syncthreads();
    if (t == 0) {
        float d = sb[0] + sb[1] + sb[2] + sb[3];
        zzlab[r] = zsq[r] + musq[lab] - 2.f * d;
    }
}

// ---- gemm_lse: S = z_bf @ mu_bf^T (128x128 tiles, bf16 MFMA), fused epilogue:
//      row_sumexp[b] += sum_c exp(S - 0.5*musq[c]);  sS += sum_{c<1000} S.
__global__ __launch_bounds__(256) void gemm_lse(const ushort_t* __restrict__ zb,
                                                const ushort_t* __restrict__ mub,
                                                const float* __restrict__ musq,
                                                float* __restrict__ row_sumexp,
                                                float* __restrict__ sS) {
    __shared__ ushort_t smA[128 * 32];
    __shared__ ushort_t smB[128 * 32];
    const int tid = threadIdx.x;
    const int lane = tid & 63;
    const int w = tid >> 6;
    const int wrow = w >> 1, wcol = w & 1;
    const int bc = blockIdx.x, br = blockIdx.y;
    const int l15 = lane & 15;
    const int k0 = (lane >> 4) * 8;

    f32x4 acc[4][4];
#pragma unroll
    for (int m = 0; m < 4; m++)
#pragma unroll
        for (int n = 0; n < 4; n++)
#pragma unroll
            for (int j = 0; j < 4; j++) acc[m][n][j] = 0.f;

    const ushort_t* gA = zb + (size_t)br * 128 * D_;
    const ushort_t* gB = mub + (size_t)bc * 128 * D_;
    const int trow = tid >> 2;         // 0..63
    const int tcol = (tid & 3) * 8;    // element offset within 32-wide k slab

    for (int kk = 0; kk < D_; kk += 32) {
        __syncthreads();  // previous iter's LDS reads done
        GLOAD16(gA + (size_t)trow * D_ + kk + tcol, smA + tid * 8);
        GLOAD16(gA + (size_t)(trow + 64) * D_ + kk + tcol, smA + 64 * 32 + tid * 8);
        GLOAD16(gB + (size_t)trow * D_ + kk + tcol, smB + tid * 8);
        GLOAD16(gB + (size_t)(trow + 64) * D_ + kk + tcol, smB + 64 * 32 + tid * 8);
        __syncthreads();  // drains vmcnt -> staged data visible
        bf16x8 af[4], bf[4];
#pragma unroll
        for (int m = 0; m < 4; m++)
            af[m] = *(const bf16x8*)(smA + (wrow * 64 + m * 16 + l15) * 32 + k0);
#pragma unroll
        for (int n = 0; n < 4; n++)
            bf[n] = *(const bf16x8*)(smB + (wcol * 64 + n * 16 + l15) * 32 + k0);
#pragma unroll
        for (int m = 0; m < 4; m++)
#pragma unroll
            for (int n = 0; n < 4; n++)
                acc[m][n] = __builtin_amdgcn_mfma_f32_16x16x32_bf16(af[m], bf[n], acc[m][n], 0, 0, 0);
    }

    // epilogue: C/D layout col=lane&15, row=(lane>>4)*4+reg  [m89/m91 verified]
    float mq[4];
    int colv[4];
#pragma unroll
    for (int n = 0; n < 4; n++) {
        colv[n] = bc * 128 + wcol * 64 + n * 16 + l15;
        mq[n] = musq[colv[n]];  // pads hold 1e30 -> exp underflows to exactly 0
    }
    float rp[4][4];
#pragma unroll
    for (int m = 0; m < 4; m++)
#pragma unroll
        for (int j = 0; j < 4; j++) rp[m][j] = 0.f;
    float sSum = 0.f;
#pragma unroll
    for (int m = 0; m < 4; m++)
#pragma unroll
        for (int n = 0; n < 4; n++) {
            const bool valid = colv[n] < C_;
#pragma unroll
            for (int j = 0; j < 4; j++) {
                float s = acc[m][n][j];
                if (valid) sSum += s;
                rp[m][j] += __expf(s - 0.5f * mq[n]);
            }
        }
#pragma unroll
    for (int m = 0; m < 4; m++)
#pragma unroll
        for (int j = 0; j < 4; j++) {
            float v = rp[m][j];
            v += __shfl_xor(v, 1, 64);
            v += __shfl_xor(v, 2, 64);
            v += __shfl_xor(v, 4, 64);
            v += __shfl_xor(v, 8, 64);
            if (l15 == 0) {
                int grow = br * 128 + wrow * 64 + m * 16 + (lane >> 4) * 4 + j;
                atomicAdd(&row_sumexp[grow], v);
            }
        }
    sSum = waveReduce(sSum);
    if (lane == 0) atomicAdd(sS, sSum);
}

// ---- finalize: per-row LSE -> nll_joint/nll_class/cat_ce means + analytic mean(logits)
__global__ __launch_bounds__(256) void finalize(const float* __restrict__ rs,
                                                const float* __restrict__ zsq,
                                                const float* __restrict__ musq,
                                                const float* __restrict__ zzlab,
                                                const float* __restrict__ jac,
                                                const float* __restrict__ sS,
                                                float* __restrict__ out) {
    const int t = threadIdx.x;
    const float logC = logf((float)C_);
    const float invD = 1.0f / (float)D_;
    float snj = 0.f, snc = 0.f, scc = 0.f, szsq = 0.f;
    for (int r = t; r < B_; r += 256) {
        float lse = logf(rs[r]) - 0.5f * zsq[r] - logC;
        float nj = (-lse - jac[r]) * invD;
        float nc = (0.5f * zzlab[r] - jac[r]) * invD;
        snj += nj;
        snc += nc;
        scc += (nc - nj);
        szsq += zsq[r];
    }
    float smu = 0.f;
    for (int c = t; c < C_; c += 256) smu += musq[c];
    float vals[5] = {snj, snc, scc, szsq, smu};
    __shared__ float red[5][4];
#pragma unroll
    for (int i = 0; i < 5; i++) {
        float v = waveReduce(vals[i]);
        if ((t & 63) == 0) red[i][t >> 6] = v;
    }
    __syncthreads();
    if (t == 0) {
        float s[5];
#pragma unroll
        for (int i = 0; i < 5; i++) s[i] = red[i][0] + red[i][1] + red[i][2] + red[i][3];
        const float SNJ = s[0], SNC = s[1], SCC = s[2], SZSQ = s[3], SMU = s[4];
        float meanS = sS[0] / ((float)B_ * (float)C_);
        out[0] = SNJ / (float)B_;                                                  // mean nll_joint
        out[1] = -0.5f * (SZSQ / (float)B_) - 0.5f * (SMU / (float)C_) + meanS;    // mean logits
        out[2] = SNC / (float)B_;                                                  // mean nll_class
        out[3] = SCC * (float)D_ / (float)B_;                                      // mean cat_ce
    }
}

extern "C" void kernel_launch(void* const* d_in, const int* in_sizes, int n_in,
                              void* d_out, int out_size, void* d_ws, size_t ws_size,
                              hipStream_t stream) {
    const float* z = (const float*)d_in[0];
    const float* mu = (const float*)d_in[1];
    const float* jac = (const float*)d_in[2];
    const float* y = (const float*)d_in[3];
    float* out = (float*)d_out;

    char* ws = (char*)d_ws;
    const size_t OFF_ZB = 0;                               // 8192*2048*2 = 33554432
    const size_t OFF_MUB = 33554432;                       // 1024*2048*2 =  4194304
    const size_t OFF_ZSQ = OFF_MUB + 4194304;              // 8192*4
    const size_t OFF_MUSQ = OFF_ZSQ + 32768;               // 1024*4
    const size_t OFF_ZZL = OFF_MUSQ + 4096;                // 8192*4
    const size_t OFF_RS = OFF_ZZL + 32768;                 // 8192*4
    const size_t OFF_SS = OFF_RS + 32768;                  // 4
    ushort_t* zb = (ushort_t*)(ws + OFF_ZB);
    ushort_t* mub = (ushort_t*)(ws + OFF_MUB);
    float* zsq = (float*)(ws + OFF_ZSQ);
    float* musq = (float*)(ws + OFF_MUSQ);
    float* zzlab = (float*)(ws + OFF_ZZL);
    float* rs = (float*)(ws + OFF_RS);
    float* sS = (float*)(ws + OFF_SS);

    hipMemsetAsync(rs, 0, 32768 + 4, stream);  // row_sumexp + sS (ws is re-poisoned each call)

    prep_z<<<B_, 256, 0, stream>>>(z, zb, zsq);
    prep_mu<<<CP_, 256, 0, stream>>>(mu, mub, musq);
    label_dot<<<B_, 256, 0, stream>>>(y, z, mu, zsq, musq, zzlab);
    gemm_lse<<<dim3(CP_ / 128, B_ / 128), 256, 0, stream>>>(zb, mub, musq, rs, sS);
    finalize<<<1, 256, 0, stream>>>(rs, zsq, musq, zzlab, jac, sS, out);
}

// Round 3
// 214.348 us; speedup vs baseline: 1.1306x; 1.1306x over previous
//
#include <hip/hip_runtime.h>

typedef unsigned short ushort_t;
typedef unsigned int uint_t;

#define B_ 8192
#define C_ 1000
#define CP_ 1024   /* padded classes */
#define D_ 2048
#define BK_ 64

typedef short bf16x8 __attribute__((ext_vector_type(8)));
typedef float f32x4 __attribute__((ext_vector_type(4)));

typedef const __attribute__((address_space(1))) void* as1_cvp;
typedef __attribute__((address_space(3))) void* as3_vp;
#define GLOAD16(gp, lp) __builtin_amdgcn_global_load_lds((as1_cvp)(gp), (as3_vp)(lp), 16, 0, 0)

__device__ __forceinline__ ushort_t f2bf(float f) {
    uint_t x = __float_as_uint(f);
    uint_t r = (x + 0x7fffu + ((x >> 16) & 1u)) >> 16;
    return (ushort_t)r;
}

__device__ __forceinline__ float waveReduce(float v) {
#pragma unroll
    for (int o = 32; o; o >>= 1) v += __shfl_xor(v, o, 64);
    return v;
}

// ---- find_label: one wave per row, argmax of one-hot y. 32.8MB stream.
__global__ __launch_bounds__(256) void find_label(const float* __restrict__ y,
                                                  int* __restrict__ lab) {
    const int wid = (blockIdx.x * 256 + threadIdx.x) >> 6;  // row
    const int lane = threadIdx.x & 63;
    const float4* yr = (const float4*)(y + (size_t)wid * C_);
    int idx = -1;
    for (int i = lane; i < C_ / 4; i += 64) {
        float4 v = yr[i];
        if (v.x > 0.5f) idx = i * 4 + 0;
        if (v.y > 0.5f) idx = i * 4 + 1;
        if (v.z > 0.5f) idx = i * 4 + 2;
        if (v.w > 0.5f) idx = i * 4 + 3;
    }
#pragma unroll
    for (int o = 32; o; o >>= 1) idx = max(idx, __shfl_xor(idx, o, 64));
    if (lane == 0) lab[wid] = idx;
}

// ---- prep_mu: mu (f32) -> mu_bf (bf16, padded to 1024 rows), musq[c]; pads: 0 / 1e30
__global__ __launch_bounds__(256) void prep_mu(const float* __restrict__ mu,
                                               ushort_t* __restrict__ mub,
                                               float* __restrict__ musq) {
    const int c = blockIdx.x;  // 0..1023
    const int t = threadIdx.x;
    if (c < C_) {
        const float4* mr = (const float4*)(mu + (size_t)c * D_);
        float4 a = mr[t * 2];
        float4 b = mr[t * 2 + 1];
        float vals[8] = {a.x, a.y, a.z, a.w, b.x, b.y, b.z, b.w};
        ushort_t u[8];
        float ss = 0.f;
#pragma unroll
        for (int i = 0; i < 8; i++) { ss += vals[i] * vals[i]; u[i] = f2bf(vals[i]); }
        *(uint4*)(mub + (size_t)c * D_ + t * 8) = *(const uint4*)u;
        ss = waveReduce(ss);
        __shared__ float sb[4];
        if ((t & 63) == 0) sb[t >> 6] = ss;
        __syncthreads();
        if (t == 0) musq[c] = sb[0] + sb[1] + sb[2] + sb[3];
    } else {
        uint4 zero4 = {0, 0, 0, 0};
        *(uint4*)(mub + (size_t)c * D_ + t * 8) = zero4;
        if (t == 0) musq[c] = 1e30f;  // exp(S - 0.5e30) == 0 -> pads vanish from LSE
    }
}

// ---- prep_zl: ONE pass over z: cast -> zb, zsq[b], and EXACT f32 label dot
//      (fuses the old label_dot, removing its 64MB z re-read).
__global__ __launch_bounds__(256) void prep_zl(const float* __restrict__ z,
                                               const float* __restrict__ mu,
                                               const int* __restrict__ lab,
                                               const float* __restrict__ musq,
                                               ushort_t* __restrict__ zb,
                                               float* __restrict__ zsq,
                                               float* __restrict__ zzlab) {
    const int r = blockIdx.x;
    const int t = threadIdx.x;
    const int L = lab[r];  // uniform -> scalar load
    const float4* zr = (const float4*)(z + (size_t)r * D_);
    const float4* mr = (const float4*)(mu + (size_t)L * D_);
    float4 a = zr[t * 2];
    float4 b = zr[t * 2 + 1];
    float4 ma = mr[t * 2];
    float4 mb = mr[t * 2 + 1];
    float vals[8] = {a.x, a.y, a.z, a.w, b.x, b.y, b.z, b.w};
    float mv[8] = {ma.x, ma.y, ma.z, ma.w, mb.x, mb.y, mb.z, mb.w};
    ushort_t u[8];
    float ss = 0.f, dot = 0.f;
#pragma unroll
    for (int i = 0; i < 8; i++) {
        ss += vals[i] * vals[i];
        dot += vals[i] * mv[i];
        u[i] = f2bf(vals[i]);
    }
    *(uint4*)(zb + (size_t)r * D_ + t * 8) = *(const uint4*)u;
    ss = waveReduce(ss);
    dot = waveReduce(dot);
    __shared__ float sb[2][4];
    if ((t & 63) == 0) { sb[0][t >> 6] = ss; sb[1][t >> 6] = dot; }
    __syncthreads();
    if (t == 0) {
        float SS = sb[0][0] + sb[0][1] + sb[0][2] + sb[0][3];
        float DT = sb[1][0] + sb[1][1] + sb[1][2] + sb[1][3];
        zsq[r] = SS;
        zzlab[r] = SS + musq[L] - 2.f * DT;
    }
}

// ---- gemm_lse: S = z_bf @ mu_bf^T, 128x128 tile, BK=64, XOR-swizzled LDS
//      (both-sides: inverse-swizzled global source + swizzled ds_read, rule 21),
//      XCD-aware block remap. Fused epilogue: row_sumexp += sum_c exp(S - 0.5*musq);
//      sS += sum_{c<1000} S.
__global__ __launch_bounds__(256) void gemm_lse(const ushort_t* __restrict__ zb,
                                                const ushort_t* __restrict__ mub,
                                                const float* __restrict__ musq,
                                                float* __restrict__ row_sumexp,
                                                float* __restrict__ sS) {
    __shared__ ushort_t smA[128 * BK_];   // 16KB
    __shared__ ushort_t smB[128 * BK_];   // 16KB
    const int tid = threadIdx.x;
    const int lane = tid & 63;
    const int w = tid >> 6;
    const int wrow = w >> 1, wcol = w & 1;
    const int l15 = lane & 15;
    const int g = lane >> 4;

    // XCD-aware bijective remap: each XCD owns 8 contiguous br panels (A 4MB + B 4MB
    // working set per XCD instead of streaming all 32MB of A through every L2).
    const int f = blockIdx.x;           // 0..511
    const int xcd = f & 7;              // HW round-robins consecutive ids across XCDs
    const int idx = f >> 3;             // 0..63
    const int br = xcd * 8 + (idx >> 3);
    const int bc = idx & 7;

    f32x4 acc[4][4];
#pragma unroll
    for (int m = 0; m < 4; m++)
#pragma unroll
        for (int n = 0; n < 4; n++)
#pragma unroll
            for (int j = 0; j < 4; j++) acc[m][n][j] = 0.f;

    const ushort_t* gA = zb + (size_t)br * 128 * D_;
    const ushort_t* gB = mub + (size_t)bc * 128 * D_;

    // Staging: 128 rows x 8 slots (16B each) per operand = 1024 blocks; 4 iters x 256 thr.
    // LDS dest linear in (it,tid) [wave-uniform base + lane*16]; global source slot
    // inverse-swizzled s = slot' ^ (row&7) so swizzled readers see linear K.
    int st_r[4], st_s[4];
#pragma unroll
    for (int it = 0; it < 4; it++) {
        int ldi = it * 256 + tid;
        st_r[it] = ldi >> 3;
        st_s[it] = (ldi & 7) ^ (st_r[it] & 7);
    }

    for (int kk = 0; kk < D_; kk += BK_) {
        __syncthreads();  // previous iter's LDS reads done
#pragma unroll
        for (int it = 0; it < 4; it++) {
            GLOAD16(gA + (size_t)st_r[it] * D_ + kk + st_s[it] * 8, smA + (it * 256 + tid) * 8);
            GLOAD16(gB + (size_t)st_r[it] * D_ + kk + st_s[it] * 8, smB + (it * 256 + tid) * 8);
        }
        __syncthreads();  // drains vmcnt -> staged data visible
#pragma unroll
        for (int ks = 0; ks < 2; ks++) {
            bf16x8 af[4], bfr[4];
#pragma unroll
            for (int m = 0; m < 4; m++) {
                int r = wrow * 64 + m * 16 + l15;
                int slot = (ks * 4 + g) ^ (r & 7);  // swizzled read: 2 lanes/bank (free)
                af[m] = *(const bf16x8*)(smA + r * BK_ + slot * 8);
            }
#pragma unroll
            for (int n = 0; n < 4; n++) {
                int r = wcol * 64 + n * 16 + l15;
                int slot = (ks * 4 + g) ^ (r & 7);
                bfr[n] = *(const bf16x8*)(smB + r * BK_ + slot * 8);
            }
#pragma unroll
            for (int m = 0; m < 4; m++)
#pragma unroll
                for (int n = 0; n < 4; n++)
                    acc[m][n] = __builtin_amdgcn_mfma_f32_16x16x32_bf16(af[m], bfr[n], acc[m][n], 0, 0, 0);
        }
    }

    // epilogue: C/D layout col=lane&15, row=(lane>>4)*4+reg  [m89/m91 verified]
    float mq[4];
    int colv[4];
#pragma unroll
    for (int n = 0; n < 4; n++) {
        colv[n] = bc * 128 + wcol * 64 + n * 16 + l15;
        mq[n] = musq[colv[n]];  // pads hold 1e30 -> exp underflows to exactly 0
    }
    float rp[4][4];
#pragma unroll
    for (int m = 0; m < 4; m++)
#pragma unroll
        for (int j = 0; j < 4; j++) rp[m][j] = 0.f;
    float sSum = 0.f;
#pragma unroll
    for (int m = 0; m < 4; m++)
#pragma unroll
        for (int n = 0; n < 4; n++) {
            const bool valid = colv[n] < C_;
#pragma unroll
            for (int j = 0; j < 4; j++) {
                float s = acc[m][n][j];
                if (valid) sSum += s;
                rp[m][j] += __expf(s - 0.5f * mq[n]);
            }
        }
#pragma unroll
    for (int m = 0; m < 4; m++)
#pragma unroll
        for (int j = 0; j < 4; j++) {
            float v = rp[m][j];
            v += __shfl_xor(v, 1, 64);
            v += __shfl_xor(v, 2, 64);
            v += __shfl_xor(v, 4, 64);
            v += __shfl_xor(v, 8, 64);
            if (l15 == 0) {
                int grow = br * 128 + wrow * 64 + m * 16 + (lane >> 4) * 4 + j;
                atomicAdd(&row_sumexp[grow], v);
            }
        }
    sSum = waveReduce(sSum);
    if (lane == 0) atomicAdd(sS, sSum);
}

// ---- finalize: per-row LSE -> nll_joint/nll_class/cat_ce means + analytic mean(logits)
__global__ __launch_bounds__(256) void finalize(const float* __restrict__ rs,
                                                const float* __restrict__ zsq,
                                                const float* __restrict__ musq,
                                                const float* __restrict__ zzlab,
                                                const float* __restrict__ jac,
                                                const float* __restrict__ sS,
                                                float* __restrict__ out) {
    const int t = threadIdx.x;
    const float logC = logf((float)C_);
    const float invD = 1.0f / (float)D_;
    float snj = 0.f, snc = 0.f, scc = 0.f, szsq = 0.f;
    for (int r = t; r < B_; r += 256) {
        float lse = logf(rs[r]) - 0.5f * zsq[r] - logC;
        float nj = (-lse - jac[r]) * invD;
        float nc = (0.5f * zzlab[r] - jac[r]) * invD;
        snj += nj;
        snc += nc;
        scc += (nc - nj);
        szsq += zsq[r];
    }
    float smu = 0.f;
    for (int c = t; c < C_; c += 256) smu += musq[c];
    float vals[5] = {snj, snc, scc, szsq, smu};
    __shared__ float red[5][4];
#pragma unroll
    for (int i = 0; i < 5; i++) {
        float v = waveReduce(vals[i]);
        if ((t & 63) == 0) red[i][t >> 6] = v;
    }
    __syncthreads();
    if (t == 0) {
        float s[5];
#pragma unroll
        for (int i = 0; i < 5; i++) s[i] = red[i][0] + red[i][1] + red[i][2] + red[i][3];
        const float SNJ = s[0], SNC = s[1], SCC = s[2], SZSQ = s[3], SMU = s[4];
        float meanS = sS[0] / ((float)B_ * (float)C_);
        out[0] = SNJ / (float)B_;                                                  // mean nll_joint
        out[1] = -0.5f * (SZSQ / (float)B_) - 0.5f * (SMU / (float)C_) + meanS;    // mean logits
        out[2] = SNC / (float)B_;                                                  // mean nll_class
        out[3] = SCC * (float)D_ / (float)B_;                                      // mean cat_ce
    }
}

extern "C" void kernel_launch(void* const* d_in, const int* in_sizes, int n_in,
                              void* d_out, int out_size, void* d_ws, size_t ws_size,
                              hipStream_t stream) {
    const float* z = (const float*)d_in[0];
    const float* mu = (const float*)d_in[1];
    const float* jac = (const float*)d_in[2];
    const float* y = (const float*)d_in[3];
    float* out = (float*)d_out;

    char* ws = (char*)d_ws;
    const size_t OFF_ZB = 0;                               // 8192*2048*2 = 33554432
    const size_t OFF_MUB = 33554432;                       // 1024*2048*2 =  4194304
    const size_t OFF_ZSQ = OFF_MUB + 4194304;              // 8192*4
    const size_t OFF_MUSQ = OFF_ZSQ + 32768;               // 1024*4
    const size_t OFF_ZZL = OFF_MUSQ + 4096;                // 8192*4
    const size_t OFF_RS = OFF_ZZL + 32768;                 // 8192*4
    const size_t OFF_SS = OFF_RS + 32768;                  // 4 (+pad)
    const size_t OFF_LAB = OFF_SS + 256;                   // 8192*4
    ushort_t* zb = (ushort_t*)(ws + OFF_ZB);
    ushort_t* mub = (ushort_t*)(ws + OFF_MUB);
    float* zsq = (float*)(ws + OFF_ZSQ);
    float* musq = (float*)(ws + OFF_MUSQ);
    float* zzlab = (float*)(ws + OFF_ZZL);
    float* rs = (float*)(ws + OFF_RS);
    float* sS = (float*)(ws + OFF_SS);
    int* lab = (int*)(ws + OFF_LAB);

    hipMemsetAsync(rs, 0, 32768 + 256, stream);  // row_sumexp + sS

    find_label<<<B_ / 4, 256, 0, stream>>>(y, lab);
    prep_mu<<<CP_, 256, 0, stream>>>(mu, mub, musq);
    prep_zl<<<B_, 256, 0, stream>>>(z, mu, lab, musq, zb, zsq, zzlab);
    gemm_lse<<<512, 256, 0, stream>>>(zb, mub, musq, rs, sS);
    finalize<<<1, 256, 0, stream>>>(rs, zsq, musq, zzlab, jac, sS, out);
}